// Round 9
// baseline (109.191 us; speedup 1.0000x reference)
//
#include <hip/hip_runtime.h>

// Problem constants (from reference)
constexpr int B = 16384;
constexpr int T = 256;
constexpr int D = 8;
constexpr int F = 512;
constexpr int C = 16;
constexpr int L = 256;  // 2^D

typedef float f32x4 __attribute__((ext_vector_type(4)));

struct FP { int fidx; float thr; };  // packed per-(t,d) node info, 8 B

// Kernel 1: per (t,d) argmax over F=512 feature weights, first-occurrence
// tie-break to match jnp.argmax. One wave per row; 4 rows per 256-thread block.
__global__ __launch_bounds__(256) void node_prep_kernel(
    const float* __restrict__ fw,      // (T, D, F)
    const float* __restrict__ thr,     // (T, D)
    FP* __restrict__ packed)           // (T*D)
{
    const int wave = threadIdx.x >> 6;
    const int lane = threadIdx.x & 63;
    const int row  = blockIdx.x * 4 + wave;          // [0, T*D)
    const float* base = fw + (size_t)row * F;

    float best = -INFINITY;
    int bidx = 0;
#pragma unroll
    for (int k = 0; k < F / 64; ++k) {
        const int idx = lane + k * 64;
        const float v = base[idx];
        if (v > best) { best = v; bidx = idx; }
    }
#pragma unroll
    for (int off = 32; off >= 1; off >>= 1) {
        const float ov = __shfl_xor(best, off);
        const int   oi = __shfl_xor(bidx, off);
        if (ov > best || (ov == best && oi < bidx)) { best = ov; bidx = oi; }
    }
    if (lane == 0) {
        FP p;
        p.fidx = bidx;
        p.thr  = thr[row];
        packed[row] = p;
    }
}

// Kernel 1b: responses fp32 -> bf16 (RNE). 4 MB -> 2 MB once per call.
// Each thread converts 8 floats; 2048 blocks x 256 threads.
__device__ __forceinline__ unsigned int bf16_rne(float f) {
    const unsigned int u = __float_as_uint(f);
    return (u + 0x7fffu + ((u >> 16) & 1u)) >> 16;
}
__global__ __launch_bounds__(256) void convert_kernel(
    const float* __restrict__ resp,       // (T*L*C)
    unsigned int* __restrict__ rb)        // (T*L*C/2) packed bf16 pairs
{
    const int i = blockIdx.x * 256 + threadIdx.x;   // 8 floats per thread
    const float4* s = reinterpret_cast<const float4*>(resp) + i * 2;
    const float4 a = s[0], b = s[1];
    uint4 o;
    o.x = bf16_rne(a.x) | (bf16_rne(a.y) << 16);
    o.y = bf16_rne(a.z) | (bf16_rne(a.w) << 16);
    o.z = bf16_rne(b.x) | (bf16_rne(b.y) << 16);
    o.w = bf16_rne(b.z) | (bf16_rne(b.w) << 16);
    reinterpret_cast<uint4*>(rb)[i] = o;
}

// Kernel 2a: decisions only. 4 samples per block; stage x rows in LDS;
// thread t computes tree t's decision byte for 4 samples; pack via LDS and
// write 1 KB per block coalesced. dec layout: dec[b][t] bytes, row = 256 B.
__global__ __launch_bounds__(256) void decide_kernel(
    const float* __restrict__ x,          // (B, F)
    const FP* __restrict__ packed,        // (T*D)
    unsigned int* __restrict__ dec)       // (B * 64) words
{
    __shared__ float xrow[4][F];             // 8 KB
    __shared__ unsigned char sdec[4][T];     // 1 KB

    const int b0  = blockIdx.x * 4;
    const int tid = threadIdx.x;

    {
        const float4* xs = reinterpret_cast<const float4*>(x + (size_t)b0 * F);
        float4* xl = reinterpret_cast<float4*>(&xrow[0][0]);
        xl[tid]       = xs[tid];
        xl[tid + 256] = xs[tid + 256];
    }
    __syncthreads();

    {
        const int2* p2 = reinterpret_cast<const int2*>(packed) + tid * D;
        int2 raw[D];
#pragma unroll
        for (int d = 0; d < D; ++d) raw[d] = p2[d];
        int dec0 = 0, dec1 = 0, dec2 = 0, dec3 = 0;
#pragma unroll
        for (int d = 0; d < D; ++d) {
            const int   f  = raw[d].x;
            const float th = __int_as_float(raw[d].y);
            const int   p  = 128 >> d;            // powers = 2^(D-1-d)
            dec0 |= (xrow[0][f] > th) ? p : 0;
            dec1 |= (xrow[1][f] > th) ? p : 0;
            dec2 |= (xrow[2][f] > th) ? p : 0;
            dec3 |= (xrow[3][f] > th) ? p : 0;
        }
        sdec[0][tid] = (unsigned char)dec0;
        sdec[1][tid] = (unsigned char)dec1;
        sdec[2][tid] = (unsigned char)dec2;
        sdec[3][tid] = (unsigned char)dec3;
    }
    __syncthreads();

    dec[blockIdx.x * 256 + tid] = reinterpret_cast<const unsigned int*>(&sdec[0][0])[tid];
}

// Kernel 2b: gathers from the bf16 table. One wave per sample; no LDS/barriers.
// lane: tree-slot = lane>>2 (0..15), channel-quad = lane&3. 4 consecutive
// lanes cover one 32 B bf16 leaf row. 16 independent uint2 gathers in a named
// register array; unpack bf16->f32 and accumulate; butterfly reduce; f32x4 out.
__global__ __launch_bounds__(256, 4) void gather_kernel(
    const unsigned int* __restrict__ dec,   // (B * 64) words
    const unsigned short* __restrict__ rb,  // bf16 (T, L, C)
    float* __restrict__ out)                // (B, C)
{
    const int tid  = threadIdx.x;
    const int w    = tid >> 6;
    const int lane = tid & 63;
    const int s    = blockIdx.x * 4 + w;   // sample

    const unsigned int w0 = dec[s * 64 + lane];

    const int wsel = lane >> 4;
    const int bsel = ((lane >> 2) & 3) * 8;       // byte within word = t&3
    // ushort offset: tree-slot<<12 | channel<<2  (+ kk<<16 | dd<<4 at use)
    const int lbase = ((lane >> 2) << 12) | ((lane & 3) << 2);

    int dw[16];
#pragma unroll
    for (int kk = 0; kk < 16; ++kk) dw[kk] = __shfl((int)w0, 4 * kk + wsel);

    uint2 r[16];
#pragma unroll
    for (int kk = 0; kk < 16; ++kk) {
        const int dd = (dw[kk] >> bsel) & 255;
        r[kk] = *reinterpret_cast<const uint2*>(rb + (kk << 16) + (dd << 4) + lbase);
    }

    float4 acc = make_float4(0.f, 0.f, 0.f, 0.f);
#pragma unroll
    for (int kk = 0; kk < 16; ++kk) {
        acc.x += __uint_as_float(r[kk].x << 16);
        acc.y += __uint_as_float(r[kk].x & 0xffff0000u);
        acc.z += __uint_as_float(r[kk].y << 16);
        acc.w += __uint_as_float(r[kk].y & 0xffff0000u);
    }

    // reduce across tree-slot bits (lane bits 2..5)
#pragma unroll
    for (int off = 4; off <= 32; off <<= 1) {
        acc.x += __shfl_xor(acc.x, off);
        acc.y += __shfl_xor(acc.y, off);
        acc.z += __shfl_xor(acc.z, off);
        acc.w += __shfl_xor(acc.w, off);
    }

    if (lane < 4) {
        const float sc = 1.0f / T;
        f32x4 o = { acc.x * sc, acc.y * sc, acc.z * sc, acc.w * sc };
        *reinterpret_cast<f32x4*>(out + ((size_t)s << 4) + (lane << 2)) = o;
    }
}

extern "C" void kernel_launch(void* const* d_in, const int* in_sizes, int n_in,
                              void* d_out, int out_size, void* d_ws, size_t ws_size,
                              hipStream_t stream) {
    const float* x         = (const float*)d_in[0];  // (B, F)
    const float* fw        = (const float*)d_in[1];  // (T, D, F)
    const float* thr       = (const float*)d_in[2];  // (T, D)
    const float* responses = (const float*)d_in[3];  // (T, L, C)
    float* out             = (float*)d_out;          // (B, C)

    FP* packed          = (FP*)d_ws;                                  // 16 KB
    unsigned int* dec   = (unsigned int*)((char*)d_ws + (1 << 16));   // 4 MB
    unsigned int* rb    = (unsigned int*)((char*)d_ws + (5 << 20));   // 2 MB bf16

    node_prep_kernel<<<(T * D) / 4, 256, 0, stream>>>(fw, thr, packed);
    convert_kernel<<<(T * L * C) / 8 / 256, 256, 0, stream>>>(responses, rb);
    decide_kernel<<<B / 4, 256, 0, stream>>>(x, packed, dec);
    gather_kernel<<<B / 4, 256, 0, stream>>>(dec, (const unsigned short*)rb, out);
}

// Round 10
// 101.693 us; speedup vs baseline: 1.0737x; 1.0737x over previous
//
#include <hip/hip_runtime.h>

// Problem constants (from reference)
constexpr int B = 16384;
constexpr int T = 256;
constexpr int D = 8;
constexpr int F = 512;
constexpr int C = 16;
constexpr int L = 256;  // 2^D

typedef float f32x4 __attribute__((ext_vector_type(4)));

struct FP { int fidx; float thr; };  // packed per-(t,d) node info, 8 B

__device__ __forceinline__ unsigned int bf16_rne(float f) {
    const unsigned int u = __float_as_uint(f);
    return (u + 0x7fffu + ((u >> 16) & 1u)) >> 16;
}

// Kernel 1 (fused prep): blocks [0,512) do per-(t,d) argmax -> packed table;
// blocks [512,1024) convert responses fp32 -> packed bf16 pairs (RNE).
__global__ __launch_bounds__(256) void prep_kernel(
    const float* __restrict__ fw,      // (T, D, F)
    const float* __restrict__ thr,     // (T, D)
    const float* __restrict__ resp,    // (T*L*C)
    FP* __restrict__ packed,           // (T*D)
    unsigned int* __restrict__ rb)     // (T*L*C/2) bf16 pairs
{
    if (blockIdx.x < 512) {
        // argmax over F=512, first-occurrence tie-break (jnp.argmax)
        const int wave = threadIdx.x >> 6;
        const int lane = threadIdx.x & 63;
        const int row  = blockIdx.x * 4 + wave;          // [0, T*D)
        const float* base = fw + (size_t)row * F;

        float best = -INFINITY;
        int bidx = 0;
#pragma unroll
        for (int k = 0; k < F / 64; ++k) {
            const int idx = lane + k * 64;
            const float v = base[idx];
            if (v > best) { best = v; bidx = idx; }
        }
#pragma unroll
        for (int off = 32; off >= 1; off >>= 1) {
            const float ov = __shfl_xor(best, off);
            const int   oi = __shfl_xor(bidx, off);
            if (ov > best || (ov == best && oi < bidx)) { best = ov; bidx = oi; }
        }
        if (lane == 0) {
            FP p;
            p.fidx = bidx;
            p.thr  = thr[row];
            packed[row] = p;
        }
    } else {
        // responses fp32 -> bf16, 8 floats per thread
        const int i = (blockIdx.x - 512) * 256 + threadIdx.x;
        const float4* s = reinterpret_cast<const float4*>(resp) + i * 2;
        const float4 a = s[0], b = s[1];
        uint4 o;
        o.x = bf16_rne(a.x) | (bf16_rne(a.y) << 16);
        o.y = bf16_rne(a.z) | (bf16_rne(a.w) << 16);
        o.z = bf16_rne(b.x) | (bf16_rne(b.y) << 16);
        o.w = bf16_rne(b.z) | (bf16_rne(b.w) << 16);
        reinterpret_cast<uint4*>(rb)[i] = o;
    }
}

// Kernel 2 (fused decide+gather): 4 samples per block, 4096 blocks.
// Phase 1: stage 4 x-rows (8 KB) in LDS via float4.
// Phase 2: thread t computes decision bytes for tree t, samples 0..3 -> LDS.
// Phase 3: wave w owns sample w. lane = tree-slot(lane>>2) x channel-quad
//          (lane&3); 4 consecutive lanes cover one 32 B bf16 leaf row.
//          16 independent uint2 gathers in a named register array (all in
//          flight); unpack bf16->f32, accumulate, butterfly-reduce over
//          slot bits, f32x4 store from lanes 0..3.
__global__ __launch_bounds__(256, 4) void forest_kernel(
    const float* __restrict__ x,            // (B, F)
    const FP* __restrict__ packed,          // (T*D)
    const unsigned short* __restrict__ rb,  // bf16 (T, L, C)
    float* __restrict__ out)                // (B, C)
{
    __shared__ float xrow[4][F];             // 8 KB
    __shared__ unsigned char sdec[4][T];     // 1 KB

    const int b0  = blockIdx.x * 4;
    const int tid = threadIdx.x;

    // Phase 1
    {
        const float4* xs = reinterpret_cast<const float4*>(x + (size_t)b0 * F);
        float4* xl = reinterpret_cast<float4*>(&xrow[0][0]);
        xl[tid]       = xs[tid];
        xl[tid + 256] = xs[tid + 256];
    }
    __syncthreads();

    // Phase 2
    {
        const int2* p2 = reinterpret_cast<const int2*>(packed) + tid * D;
        int2 raw[D];
#pragma unroll
        for (int d = 0; d < D; ++d) raw[d] = p2[d];
        int dec0 = 0, dec1 = 0, dec2 = 0, dec3 = 0;
#pragma unroll
        for (int d = 0; d < D; ++d) {
            const int   f  = raw[d].x;
            const float th = __int_as_float(raw[d].y);
            const int   p  = 128 >> d;            // powers = 2^(D-1-d)
            dec0 |= (xrow[0][f] > th) ? p : 0;
            dec1 |= (xrow[1][f] > th) ? p : 0;
            dec2 |= (xrow[2][f] > th) ? p : 0;
            dec3 |= (xrow[3][f] > th) ? p : 0;
        }
        sdec[0][tid] = (unsigned char)dec0;
        sdec[1][tid] = (unsigned char)dec1;
        sdec[2][tid] = (unsigned char)dec2;
        sdec[3][tid] = (unsigned char)dec3;
    }
    __syncthreads();

    // Phase 3: wave w -> sample b0+w.
    const int w    = tid >> 6;
    const int lane = tid & 63;

    const int* pw  = reinterpret_cast<const int*>(&sdec[w][0]);
    const int wsel = lane >> 4;
    const int bsel = ((lane >> 2) & 3) * 8;       // byte within word
    // ushort offset: tree-slot<<12 | channel-quad<<2 (+ kk<<16 | dd<<4)
    const int lbase = ((lane >> 2) << 12) | ((lane & 3) << 2);

    int dw[16];
#pragma unroll
    for (int kk = 0; kk < 16; ++kk) dw[kk] = pw[4 * kk + wsel];

    uint2 r[16];
#pragma unroll
    for (int kk = 0; kk < 16; ++kk) {
        const int dd = (dw[kk] >> bsel) & 255;
        r[kk] = *reinterpret_cast<const uint2*>(rb + (kk << 16) + (dd << 4) + lbase);
    }

    float4 acc = make_float4(0.f, 0.f, 0.f, 0.f);
#pragma unroll
    for (int kk = 0; kk < 16; ++kk) {
        acc.x += __uint_as_float(r[kk].x << 16);
        acc.y += __uint_as_float(r[kk].x & 0xffff0000u);
        acc.z += __uint_as_float(r[kk].y << 16);
        acc.w += __uint_as_float(r[kk].y & 0xffff0000u);
    }

    // reduce across tree-slot bits (lane bits 2..5)
#pragma unroll
    for (int off = 4; off <= 32; off <<= 1) {
        acc.x += __shfl_xor(acc.x, off);
        acc.y += __shfl_xor(acc.y, off);
        acc.z += __shfl_xor(acc.z, off);
        acc.w += __shfl_xor(acc.w, off);
    }

    if (lane < 4) {
        const float sc = 1.0f / T;
        f32x4 o = { acc.x * sc, acc.y * sc, acc.z * sc, acc.w * sc };
        *reinterpret_cast<f32x4*>(out + ((size_t)(b0 + w) << 4) + (lane << 2)) = o;
    }
}

extern "C" void kernel_launch(void* const* d_in, const int* in_sizes, int n_in,
                              void* d_out, int out_size, void* d_ws, size_t ws_size,
                              hipStream_t stream) {
    const float* x         = (const float*)d_in[0];  // (B, F)
    const float* fw        = (const float*)d_in[1];  // (T, D, F)
    const float* thr       = (const float*)d_in[2];  // (T, D)
    const float* responses = (const float*)d_in[3];  // (T, L, C)
    float* out             = (float*)d_out;          // (B, C)

    FP* packed        = (FP*)d_ws;                                 // 16 KB
    unsigned int* rb  = (unsigned int*)((char*)d_ws + (1 << 16));  // 2 MB bf16

    prep_kernel<<<1024, 256, 0, stream>>>(fw, thr, responses, packed, rb);
    forest_kernel<<<B / 4, 256, 0, stream>>>(x, packed,
                                             (const unsigned short*)rb, out);
}

// Round 11
// 100.848 us; speedup vs baseline: 1.0827x; 1.0084x over previous
//
#include <hip/hip_runtime.h>

// Problem constants (from reference)
constexpr int B = 16384;
constexpr int T = 256;
constexpr int D = 8;
constexpr int F = 512;
constexpr int C = 16;
constexpr int L = 256;  // 2^D

typedef float f32x4 __attribute__((ext_vector_type(4)));

struct FP { int fidx; float thr; };  // packed per-(t,d) node info, 8 B

__device__ __forceinline__ unsigned int bf16_rne(float f) {
    const unsigned int u = __float_as_uint(f);
    return (u + 0x7fffu + ((u >> 16) & 1u)) >> 16;
}

// Kernel 1 (fused prep): blocks [0,512) do per-(t,d) argmax -> packed table;
// blocks [512,1024) convert responses fp32 -> packed bf16 pairs (RNE).
__global__ __launch_bounds__(256) void prep_kernel(
    const float* __restrict__ fw,      // (T, D, F)
    const float* __restrict__ thr,     // (T, D)
    const float* __restrict__ resp,    // (T*L*C)
    FP* __restrict__ packed,           // (T*D)
    unsigned int* __restrict__ rb)     // (T*L*C/2) bf16 pairs
{
    if (blockIdx.x < 512) {
        // argmax over F=512, first-occurrence tie-break (jnp.argmax)
        const int wave = threadIdx.x >> 6;
        const int lane = threadIdx.x & 63;
        const int row  = blockIdx.x * 4 + wave;          // [0, T*D)
        const float* base = fw + (size_t)row * F;

        float best = -INFINITY;
        int bidx = 0;
#pragma unroll
        for (int k = 0; k < F / 64; ++k) {
            const int idx = lane + k * 64;
            const float v = base[idx];
            if (v > best) { best = v; bidx = idx; }
        }
#pragma unroll
        for (int off = 32; off >= 1; off >>= 1) {
            const float ov = __shfl_xor(best, off);
            const int   oi = __shfl_xor(bidx, off);
            if (ov > best || (ov == best && oi < bidx)) { best = ov; bidx = oi; }
        }
        if (lane == 0) {
            FP p;
            p.fidx = bidx;
            p.thr  = thr[row];
            packed[row] = p;
        }
    } else {
        // responses fp32 -> bf16, 8 floats per thread
        const int i = (blockIdx.x - 512) * 256 + threadIdx.x;
        const float4* s = reinterpret_cast<const float4*>(resp) + i * 2;
        const float4 a = s[0], b = s[1];
        uint4 o;
        o.x = bf16_rne(a.x) | (bf16_rne(a.y) << 16);
        o.y = bf16_rne(a.z) | (bf16_rne(a.w) << 16);
        o.z = bf16_rne(b.x) | (bf16_rne(b.y) << 16);
        o.w = bf16_rne(b.z) | (bf16_rne(b.w) << 16);
        reinterpret_cast<uint4*>(rb)[i] = o;
    }
}

// Kernel 2: 4 samples per block, ONE barrier, wave-autonomous after staging.
// Stage: 4 x-rows (8 KB) + node table transposed tbl[d][t] (16 KB). Sync.
// Then wave w owns sample w end-to-end, no further barriers:
//   decide: lane computes trees 4*lane..4*lane+3 (16 ds_read_b128 table +
//           32 random LDS x reads), packs 4 decision bytes into one u32;
//   exchange: 16 __shfl's give each lane the decision words it needs;
//   gather: 16 independent uint2 bf16-leaf gathers (register array, all in
//           flight), unpack+accumulate f32, butterfly reduce over slot bits,
//   f32x4 store from lanes 0..3.
__global__ __launch_bounds__(256, 4) void forest_kernel(
    const float* __restrict__ x,            // (B, F)
    const FP* __restrict__ packed,          // (T*D)
    const unsigned short* __restrict__ rb,  // bf16 (T, L, C)
    float* __restrict__ out)                // (B, C)
{
    __shared__ float xrow[4][F];   // 8 KB
    __shared__ int2  tbl[D][T];    // 16 KB: tbl[d][t] = {fidx, thr-bits}

    const int b0  = blockIdx.x * 4;
    const int tid = threadIdx.x;

    // Stage x rows: 512 float4, 2 per thread, coalesced; b128 LDS writes.
    {
        const float4* xs = reinterpret_cast<const float4*>(x + (size_t)b0 * F);
        float4* xl = reinterpret_cast<float4*>(&xrow[0][0]);
        xl[tid]       = xs[tid];
        xl[tid + 256] = xs[tid + 256];
    }
    // Stage node table transposed: thread tid reads tree tid's row (64 B
    // coalesced) and scatters to tbl[d][tid] (stride-8B lanes: conflict-free).
    {
        const int4* tp = reinterpret_cast<const int4*>(packed + (size_t)tid * D);
        const int4 q0 = tp[0], q1 = tp[1], q2 = tp[2], q3 = tp[3];
        tbl[0][tid] = make_int2(q0.x, q0.y);
        tbl[1][tid] = make_int2(q0.z, q0.w);
        tbl[2][tid] = make_int2(q1.x, q1.y);
        tbl[3][tid] = make_int2(q1.z, q1.w);
        tbl[4][tid] = make_int2(q2.x, q2.y);
        tbl[5][tid] = make_int2(q2.z, q2.w);
        tbl[6][tid] = make_int2(q3.x, q3.y);
        tbl[7][tid] = make_int2(q3.z, q3.w);
    }
    __syncthreads();   // the ONLY barrier

    const int w    = tid >> 6;
    const int lane = tid & 63;

    // ---- decide: trees 4*lane .. 4*lane+3, sample b0+w ----
    const float* xb = &xrow[w][0];
    unsigned int dec = 0;   // byte i = decision of tree 4*lane+i
#pragma unroll
    for (int d = 0; d < D; ++d) {
        const int4 a = *reinterpret_cast<const int4*>(&tbl[d][4 * lane]);
        const int4 b = *reinterpret_cast<const int4*>(&tbl[d][4 * lane + 2]);
        const unsigned int bit = 128u >> d;       // powers = 2^(D-1-d)
        if (xb[a.x] > __int_as_float(a.y)) dec |= bit;
        if (xb[a.z] > __int_as_float(a.w)) dec |= bit << 8;
        if (xb[b.x] > __int_as_float(b.y)) dec |= bit << 16;
        if (xb[b.z] > __int_as_float(b.w)) dec |= bit << 24;
    }

    // ---- exchange: lane (slot s=lane>>2, quad q=lane&3) needs, for kk,
    // tree 16kk+s = word from lane 4kk+(s>>2), byte s&3. 16 shfls, no LDS.
    const int src  = lane >> 4;                   // (s>>2)
    const int bsel = ((lane >> 2) & 3) * 8;       // (s&3)*8
    int dw[16];
#pragma unroll
    for (int kk = 0; kk < 16; ++kk) dw[kk] = __shfl((int)dec, 4 * kk + src);

    // ---- gather: ushort index = kk<<16 | s<<12 | dd<<4 | q<<2 ----
    const int lbase = ((lane >> 2) << 12) | ((lane & 3) << 2);

    uint2 r[16];
#pragma unroll
    for (int kk = 0; kk < 16; ++kk) {
        const int dd = (dw[kk] >> bsel) & 255;
        r[kk] = *reinterpret_cast<const uint2*>(rb + (kk << 16) + (dd << 4) + lbase);
    }

    float4 acc = make_float4(0.f, 0.f, 0.f, 0.f);
#pragma unroll
    for (int kk = 0; kk < 16; ++kk) {
        acc.x += __uint_as_float(r[kk].x << 16);
        acc.y += __uint_as_float(r[kk].x & 0xffff0000u);
        acc.z += __uint_as_float(r[kk].y << 16);
        acc.w += __uint_as_float(r[kk].y & 0xffff0000u);
    }

    // reduce across tree-slot bits (lane bits 2..5)
#pragma unroll
    for (int off = 4; off <= 32; off <<= 1) {
        acc.x += __shfl_xor(acc.x, off);
        acc.y += __shfl_xor(acc.y, off);
        acc.z += __shfl_xor(acc.z, off);
        acc.w += __shfl_xor(acc.w, off);
    }

    if (lane < 4) {
        const float sc = 1.0f / T;
        f32x4 o = { acc.x * sc, acc.y * sc, acc.z * sc, acc.w * sc };
        *reinterpret_cast<f32x4*>(out + ((size_t)(b0 + w) << 4) + (lane << 2)) = o;
    }
}

extern "C" void kernel_launch(void* const* d_in, const int* in_sizes, int n_in,
                              void* d_out, int out_size, void* d_ws, size_t ws_size,
                              hipStream_t stream) {
    const float* x         = (const float*)d_in[0];  // (B, F)
    const float* fw        = (const float*)d_in[1];  // (T, D, F)
    const float* thr       = (const float*)d_in[2];  // (T, D)
    const float* responses = (const float*)d_in[3];  // (T, L, C)
    float* out             = (float*)d_out;          // (B, C)

    FP* packed        = (FP*)d_ws;                                 // 16 KB
    unsigned int* rb  = (unsigned int*)((char*)d_ws + (1 << 16));  // 2 MB bf16

    prep_kernel<<<1024, 256, 0, stream>>>(fw, thr, responses, packed, rb);
    forest_kernel<<<B / 4, 256, 0, stream>>>(x, packed,
                                             (const unsigned short*)rb, out);
}